// Round 14
// baseline (120.862 us; speedup 1.0000x reference)
//
#include <hip/hip_runtime.h>
#include <hip/hip_bf16.h>
#include <math.h>

// Averaged Hausdorff distance between two 16384x3 fp32 point sets.
// (R13 resubmitted as R14 — R13 bench hit GPUAcquisitionTimeout, never ran.)
// R12 post-mortem: lifting the VGPR cap removed R9's scratch traffic
// (WRITE_SIZE exactly 8MB) but compiler still chose 68 VGPRs and pair time
// was unchanged (51.7 vs 50.9) -> registers were NOT the limiter.
// OccupancyPercent=18 (512 blocks = 2/CU = 2 waves/SIMD): issue eff
// tracks occupancy across all rounds. Practical fma ceiling ~103TF (m07)
// -> pair floor ~36us; we're at 71%.
// R13 single change: CHUNK 256->128 => grid (4,128,2)=1024 blocks = 4/CU
// = 4 waves/SIMD (2x TLP). LDS reads/pair are CHUNK-invariant. Part array
// back to 16.8MB; R12's parallel reduce handles it (R9's serial one could
// not). launch_bounds stays (256,2) so the spill can't return.

#define NPTS   16384
#define BLK    256
#define P      16                   // outer points per thread
#define CHUNK  128                  // inner points per LDS tile
#define XBLK   (NPTS / (BLK * P))   // 4
#define SPLIT  (NPTS / CHUNK)       // 128
#define RBLK   (NPTS / BLK)         // 64 reduce blocks per dir
#define FLTMAX 3.402823466e+38f

// ---------------- main path (no atomics) ----------------

__global__ __launch_bounds__(BLK, 2)
void pair_part_kernel(const float* __restrict__ s1, const float* __restrict__ s2,
                      float* __restrict__ part /* [2][SPLIT][NPTS] */) {
    __shared__ float4 tile[CHUNK];

    const int tid = threadIdx.x;
    const int x   = blockIdx.x;
    const int y   = blockIdx.y;
    const int dir = blockIdx.z;
    const float* __restrict__ A = dir ? s2 : s1;
    const float* __restrict__ B = dir ? s1 : s2;

    const int obase = x * (BLK * P);
    const int cbase = y * CHUNK;

    // Stage inner tile once: float4(bx,by,bz,|b|^2).
    if (tid < CHUNK) {
        int g = cbase + tid;
        float bx = B[3 * g], by = B[3 * g + 1], bz = B[3 * g + 2];
        tile[tid] = make_float4(bx, by, bz, fmaf(bx, bx, fmaf(by, by, bz * bz)));
    }
    __syncthreads();

    float m2x[P], m2y[P], m2z[P], sa[P], mn[P];
    #pragma unroll
    for (int p = 0; p < P; ++p) {
        int i = obase + p * BLK + tid;
        float ax = A[3 * i], ay = A[3 * i + 1], az = A[3 * i + 2];
        sa[p]  = fmaf(ax, ax, fmaf(ay, ay, az * az));   // |a|^2
        m2x[p] = -(ax + ax); m2y[p] = -(ay + ay); m2z[p] = -(az + az);
        mn[p]  = FLTMAX;
    }

    // One broadcast ds_read_b128 serves P*64 = 1024 pairs.
    // t = fma(-2ax,bx, fma(-2ay,by, fma(-2az,bz, |b|^2))) = d^2 - |a|^2.
    for (int j = 0; j < CHUNK; j += 4) {
        float4 b0 = tile[j], b1 = tile[j + 1], b2 = tile[j + 2], b3 = tile[j + 3];
        #pragma unroll
        for (int p = 0; p < P; ++p) {
            float t0 = fmaf(m2x[p], b0.x, fmaf(m2y[p], b0.y, fmaf(m2z[p], b0.z, b0.w)));
            float t1 = fmaf(m2x[p], b1.x, fmaf(m2y[p], b1.y, fmaf(m2z[p], b1.z, b1.w)));
            float t2 = fmaf(m2x[p], b2.x, fmaf(m2y[p], b2.y, fmaf(m2z[p], b2.z, b2.w)));
            float t3 = fmaf(m2x[p], b3.x, fmaf(m2y[p], b3.y, fmaf(m2z[p], b3.z, b3.w)));
            float u = fminf(fminf(mn[p], t0), t1);   // 2x v_min3_f32
            mn[p] = fminf(fminf(u, t2), t3);
        }
    }

    // Plain coalesced stores of partial min d^2 (clamped >= 0).
    float* dst = part + ((size_t)dir * SPLIT + y) * NPTS + obase;
    #pragma unroll
    for (int p = 0; p < P; ++p) {
        dst[p * BLK + tid] = fmaxf(sa[p] + mn[p], 0.0f);
    }
}

__global__ __launch_bounds__(BLK)
void reduce_part_kernel(const float* __restrict__ part, double* __restrict__ blocksum) {
    const int tid = threadIdx.x;
    const int dir = blockIdx.y;                       // 0 or 1
    const int i = blockIdx.x * BLK + tid;

    const float* rp = part + (size_t)dir * SPLIT * NPTS + i;
    float m = FLTMAX;
    #pragma unroll 8
    for (int y = 0; y < SPLIT; ++y) m = fminf(m, rp[(size_t)y * NPTS]);

    double s = (double)sqrtf(m);
    for (int off = 32; off > 0; off >>= 1) s += __shfl_down(s, off);
    __shared__ double w[4];
    if ((tid & 63) == 0) w[tid >> 6] = s;
    __syncthreads();
    if (tid == 0) blocksum[dir * RBLK + blockIdx.x] = w[0] + w[1] + w[2] + w[3];
}

__global__ void final_kernel(const double* __restrict__ blocksum, float* __restrict__ out) {
    const int tid = threadIdx.x;      // 128 threads (2 waves)
    double s = blocksum[tid];
    for (int off = 32; off > 0; off >>= 1) s += __shfl_down(s, off);
    __shared__ double w[2];
    if ((tid & 63) == 0) w[tid >> 6] = s;
    __syncthreads();
    if (tid == 0) out[0] = (float)((w[0] + w[1]) / (double)NPTS);
}

// ---------------- fallback path (atomicMin, small ws) ----------------

__global__ __launch_bounds__(BLK)
void fb_init(unsigned int* rowmin, unsigned int* colmin) {
    int i = blockIdx.x * BLK + threadIdx.x;
    if (i < NPTS) { rowmin[i] = 0x7F7FFFFFu; colmin[i] = 0x7F7FFFFFu; }
}

__global__ __launch_bounds__(BLK, 2)
void fb_pair(const float* __restrict__ s1, const float* __restrict__ s2,
             unsigned int* __restrict__ rowmin, unsigned int* __restrict__ colmin) {
    __shared__ float4 tile[CHUNK];
    const int tid = threadIdx.x;
    const int dir = blockIdx.z;
    const float* __restrict__ A = dir ? s2 : s1;
    const float* __restrict__ B = dir ? s1 : s2;
    unsigned int* __restrict__ outmin = dir ? colmin : rowmin;
    const int obase = blockIdx.x * (BLK * P);
    const int cbase = blockIdx.y * CHUNK;

    if (tid < CHUNK) {
        int g = cbase + tid;
        float bx = B[3 * g], by = B[3 * g + 1], bz = B[3 * g + 2];
        tile[tid] = make_float4(bx, by, bz, fmaf(bx, bx, fmaf(by, by, bz * bz)));
    }
    __syncthreads();

    float m2x[P], m2y[P], m2z[P], sa[P], mn[P];
    #pragma unroll
    for (int p = 0; p < P; ++p) {
        int i = obase + p * BLK + tid;
        float ax = A[3 * i], ay = A[3 * i + 1], az = A[3 * i + 2];
        sa[p]  = fmaf(ax, ax, fmaf(ay, ay, az * az));
        m2x[p] = -(ax + ax); m2y[p] = -(ay + ay); m2z[p] = -(az + az);
        mn[p]  = FLTMAX;
    }
    for (int j = 0; j < CHUNK; j += 4) {
        float4 b0 = tile[j], b1 = tile[j + 1], b2 = tile[j + 2], b3 = tile[j + 3];
        #pragma unroll
        for (int p = 0; p < P; ++p) {
            float t0 = fmaf(m2x[p], b0.x, fmaf(m2y[p], b0.y, fmaf(m2z[p], b0.z, b0.w)));
            float t1 = fmaf(m2x[p], b1.x, fmaf(m2y[p], b1.y, fmaf(m2z[p], b1.z, b1.w)));
            float t2 = fmaf(m2x[p], b2.x, fmaf(m2y[p], b2.y, fmaf(m2z[p], b2.z, b2.w)));
            float t3 = fmaf(m2x[p], b3.x, fmaf(m2y[p], b3.y, fmaf(m2z[p], b3.z, b3.w)));
            float u = fminf(fminf(mn[p], t0), t1);
            mn[p] = fminf(fminf(u, t2), t3);
        }
    }
    #pragma unroll
    for (int p = 0; p < P; ++p) {
        float d2 = fmaxf(sa[p] + mn[p], 0.0f);
        atomicMin(&outmin[obase + p * BLK + tid], __float_as_uint(d2));
    }
}

__global__ __launch_bounds__(BLK)
void fb_reduce(const unsigned int* __restrict__ rowmin, const unsigned int* __restrict__ colmin,
               double* __restrict__ blocksum) {
    const int tid = threadIdx.x;
    const int i = blockIdx.x * BLK + tid;
    double s = (double)sqrtf(__uint_as_float(rowmin[i]))
             + (double)sqrtf(__uint_as_float(colmin[i]));
    for (int off = 32; off > 0; off >>= 1) s += __shfl_down(s, off);
    __shared__ double w[4];
    if ((tid & 63) == 0) w[tid >> 6] = s;
    __syncthreads();
    if (tid == 0) {
        blocksum[blockIdx.x] = w[0] + w[1] + w[2] + w[3];
        blocksum[RBLK + blockIdx.x] = 0.0;   // keep final_kernel's 128-wide sum valid
    }
}

// ---------------- launch ----------------

extern "C" void kernel_launch(void* const* d_in, const int* in_sizes, int n_in,
                              void* d_out, int out_size, void* d_ws, size_t ws_size,
                              hipStream_t stream) {
    const float* s1 = (const float*)d_in[0];
    const float* s2 = (const float*)d_in[1];
    float* out = (float*)d_out;

    const size_t part_elems = (size_t)2 * SPLIT * NPTS;          // 4M floats = 16.8 MB
    const size_t need = part_elems * sizeof(float) + 2 * RBLK * sizeof(double);

    if (ws_size >= need) {
        float* part = (float*)d_ws;
        double* blocksum = (double*)(part + part_elems);

        dim3 grid(XBLK, SPLIT, 2);                               // 4 x 128 x 2 = 1024
        pair_part_kernel<<<grid, BLK, 0, stream>>>(s1, s2, part);
        reduce_part_kernel<<<dim3(RBLK, 2), BLK, 0, stream>>>(part, blocksum);
        final_kernel<<<1, 128, 0, stream>>>(blocksum, out);
    } else {
        unsigned int* rowmin = (unsigned int*)d_ws;
        unsigned int* colmin = rowmin + NPTS;
        double* blocksum = (double*)(colmin + NPTS);

        fb_init<<<NPTS / BLK, BLK, 0, stream>>>(rowmin, colmin);
        dim3 grid(XBLK, SPLIT, 2);
        fb_pair<<<grid, BLK, 0, stream>>>(s1, s2, rowmin, colmin);
        fb_reduce<<<RBLK, BLK, 0, stream>>>(rowmin, colmin, blocksum);
        final_kernel<<<1, 128, 0, stream>>>(blocksum, out);
    }
}

// Round 15
// 107.810 us; speedup vs baseline: 1.1211x; 1.1211x over previous
//
#include <hip/hip_runtime.h>
#include <hip/hip_bf16.h>
#include <math.h>

// Averaged Hausdorff distance between two 16384x3 fp32 point sets.
// R14 post-mortem: (1) pair at 58% issue ~= practical VALU ceiling (m07
// ubench itself = 66%); occupancy lever exhausted. (2) total-pair gap
// scales ~2.1us/MB of ws (harness poisons d_ws in the timed window):
// 16.8MB part array cost ~35us of overhead. (3) directed 2-pass computes
// every d^2 TWICE.
// R15: symmetric single pass. d2 = fma(-2a, b, |a|^2+|b|^2) computed once;
// register rowmin (min3) AND per-j colmin (min3 over p + 6-step shfl_xor
// butterfly + LDS atomicMin across waves + global atomicMin across 4
// x-blocks). Outputs via atomicMin into 128KB -> poison cost ~0.
// Pair work halved: floor 18.4us, predict 28-34us; total ~84-92us.

#define NPTS   16384
#define BLK    256
#define P      16                   // outer (s1) points per thread
#define CHUNK  64                   // inner (s2) points per LDS tile
#define XBLK   (NPTS / (BLK * P))   // 4
#define SPLIT  (NPTS / CHUNK)       // 256 -> grid (4,256) = 1024 blocks
#define RBLK   (NPTS / BLK)         // 64 reduce blocks
#define FLTMAX 3.402823466e+38f

__global__ __launch_bounds__(BLK)
void init_kernel(unsigned int* __restrict__ rowmin, unsigned int* __restrict__ colmin) {
    int i = blockIdx.x * BLK + threadIdx.x;   // 128 blocks cover 2*NPTS
    if (i < NPTS) rowmin[i] = 0x7F7FFFFFu;    // FLT_MAX bits
    else          colmin[i - NPTS] = 0x7F7FFFFFu;
}

__global__ __launch_bounds__(BLK, 2)
void pair_sym_kernel(const float* __restrict__ s1, const float* __restrict__ s2,
                     unsigned int* __restrict__ rowmin, unsigned int* __restrict__ colmin) {
    __shared__ float4 tile[CHUNK];            // (bx,by,bz,|b|^2)
    __shared__ unsigned int coltile[CHUNK];   // block-level colmin partials

    const int tid = threadIdx.x;
    const int obase = blockIdx.x * (BLK * P); // s1 range of this block
    const int cbase = blockIdx.y * CHUNK;     // s2 tile base

    if (tid < CHUNK) {
        int g = cbase + tid;
        float bx = s2[3 * g], by = s2[3 * g + 1], bz = s2[3 * g + 2];
        tile[tid] = make_float4(bx, by, bz, fmaf(bx, bx, fmaf(by, by, bz * bz)));
        coltile[tid] = 0x7F7FFFFFu;
    }
    __syncthreads();

    float m2x[P], m2y[P], m2z[P], sa[P], mn[P];
    #pragma unroll
    for (int p = 0; p < P; ++p) {
        int i = obase + p * BLK + tid;
        float ax = s1[3 * i], ay = s1[3 * i + 1], az = s1[3 * i + 2];
        sa[p]  = fmaf(ax, ax, fmaf(ay, ay, az * az));   // |a|^2
        m2x[p] = -(ax + ax); m2y[p] = -(ay + ay); m2z[p] = -(az + az);
        mn[p]  = FLTMAX;
    }

    // d2 = (|a|^2+|b|^2) - 2 a.b : 1 add + 3 fma per pair, computed ONCE.
    // rowmin: per-thread min3 chains. colmin: min3 over p, then 6-step
    // shfl_xor butterfly (wave) + LDS atomicMin (4 waves) per j.
    for (int jb = 0; jb < CHUNK; jb += 4) {
        float4 b0 = tile[jb], b1 = tile[jb + 1], b2 = tile[jb + 2], b3 = tile[jb + 3];
        float cm0 = FLTMAX, cm1 = FLTMAX, cm2 = FLTMAX, cm3 = FLTMAX;
        #pragma unroll
        for (int p = 0; p < P; p += 2) {
            float d0a = fmaf(m2x[p], b0.x, fmaf(m2y[p], b0.y, fmaf(m2z[p], b0.z, sa[p] + b0.w)));
            float d1a = fmaf(m2x[p], b1.x, fmaf(m2y[p], b1.y, fmaf(m2z[p], b1.z, sa[p] + b1.w)));
            float d2a = fmaf(m2x[p], b2.x, fmaf(m2y[p], b2.y, fmaf(m2z[p], b2.z, sa[p] + b2.w)));
            float d3a = fmaf(m2x[p], b3.x, fmaf(m2y[p], b3.y, fmaf(m2z[p], b3.z, sa[p] + b3.w)));
            float d0b = fmaf(m2x[p+1], b0.x, fmaf(m2y[p+1], b0.y, fmaf(m2z[p+1], b0.z, sa[p+1] + b0.w)));
            float d1b = fmaf(m2x[p+1], b1.x, fmaf(m2y[p+1], b1.y, fmaf(m2z[p+1], b1.z, sa[p+1] + b1.w)));
            float d2b = fmaf(m2x[p+1], b2.x, fmaf(m2y[p+1], b2.y, fmaf(m2z[p+1], b2.z, sa[p+1] + b2.w)));
            float d3b = fmaf(m2x[p+1], b3.x, fmaf(m2y[p+1], b3.y, fmaf(m2z[p+1], b3.z, sa[p+1] + b3.w)));
            // rowmin: 2x min3 per point
            mn[p]   = fminf(fminf(mn[p],   d0a), d1a); mn[p]   = fminf(fminf(mn[p],   d2a), d3a);
            mn[p+1] = fminf(fminf(mn[p+1], d0b), d1b); mn[p+1] = fminf(fminf(mn[p+1], d2b), d3b);
            // colmin: 1x min3 per j per point-pair
            cm0 = fminf(fminf(cm0, d0a), d0b);
            cm1 = fminf(fminf(cm1, d1a), d1b);
            cm2 = fminf(fminf(cm2, d2a), d2b);
            cm3 = fminf(fminf(cm3, d3a), d3b);
        }
        // 64-lane butterfly min (all lanes active, no divergence)
        #pragma unroll
        for (int m = 1; m <= 32; m <<= 1) {
            cm0 = fminf(cm0, __shfl_xor(cm0, m));
            cm1 = fminf(cm1, __shfl_xor(cm1, m));
            cm2 = fminf(cm2, __shfl_xor(cm2, m));
            cm3 = fminf(cm3, __shfl_xor(cm3, m));
        }
        if ((tid & 63) == 0) {   // one lane per wave merges into block partial
            atomicMin(&coltile[jb + 0], __float_as_uint(fmaxf(cm0, 0.0f)));
            atomicMin(&coltile[jb + 1], __float_as_uint(fmaxf(cm1, 0.0f)));
            atomicMin(&coltile[jb + 2], __float_as_uint(fmaxf(cm2, 0.0f)));
            atomicMin(&coltile[jb + 3], __float_as_uint(fmaxf(cm3, 0.0f)));
        }
    }
    __syncthreads();

    if (tid < CHUNK) atomicMin(&colmin[cbase + tid], coltile[tid]);  // 4 blocks/addr
    #pragma unroll
    for (int p = 0; p < P; ++p) {                                    // 256 blocks/addr
        atomicMin(&rowmin[obase + p * BLK + tid], __float_as_uint(fmaxf(mn[p], 0.0f)));
    }
}

__global__ __launch_bounds__(BLK)
void reduce_kernel(const unsigned int* __restrict__ rowmin,
                   const unsigned int* __restrict__ colmin,
                   double* __restrict__ blocksum) {
    const int tid = threadIdx.x;
    const int i = blockIdx.x * BLK + tid;
    double s = (double)sqrtf(__uint_as_float(rowmin[i]))
             + (double)sqrtf(__uint_as_float(colmin[i]));
    for (int off = 32; off > 0; off >>= 1) s += __shfl_down(s, off);
    __shared__ double w[4];
    if ((tid & 63) == 0) w[tid >> 6] = s;
    __syncthreads();
    if (tid == 0) blocksum[blockIdx.x] = w[0] + w[1] + w[2] + w[3];
}

__global__ void final_kernel(const double* __restrict__ blocksum, float* __restrict__ out) {
    const int lane = threadIdx.x;     // 64 threads
    double s = blocksum[lane];
    for (int off = 32; off > 0; off >>= 1) s += __shfl_down(s, off);
    if (lane == 0) out[0] = (float)(s / (double)NPTS);
}

extern "C" void kernel_launch(void* const* d_in, const int* in_sizes, int n_in,
                              void* d_out, int out_size, void* d_ws, size_t ws_size,
                              hipStream_t stream) {
    const float* s1 = (const float*)d_in[0];
    const float* s2 = (const float*)d_in[1];
    float* out = (float*)d_out;

    // ws: 64KB + 64KB + 512B  (total 132KB -> negligible poison overhead)
    unsigned int* rowmin = (unsigned int*)d_ws;
    unsigned int* colmin = rowmin + NPTS;
    double* blocksum = (double*)(colmin + NPTS);

    init_kernel<<<2 * NPTS / BLK, BLK, 0, stream>>>(rowmin, colmin);
    dim3 grid(XBLK, SPLIT);                    // 4 x 256 = 1024 blocks = 4/CU
    pair_sym_kernel<<<grid, BLK, 0, stream>>>(s1, s2, rowmin, colmin);
    reduce_kernel<<<RBLK, BLK, 0, stream>>>(rowmin, colmin, blocksum);
    final_kernel<<<1, 64, 0, stream>>>(blocksum, out);
}